// Round 15
// baseline (142.977 us; speedup 1.0000x reference)
//
#include <hip/hip_runtime.h>
#include <hip/hip_bf16.h>
#include <math.h>

// Problem constants
#define K_TOT 62500      // C*H*W = 4*125*125
#define KQ_TOT 15625     // K_TOT / 4 (float4 quads per batch row)
#define NJ    20         // hidden width
#define NB    512        // batch
#define HW_   15625      // 125*125
#define WW_   125
#define NKSPL 128        // number of k1 blocks along K (contiguous chunks)
#define LDSTR 68         // padded LDS row stride (floats; 17 bank-quads -> conflict-free b128)

// scratch layout inside d_out's image region (only regions NOT read by k3):
#define HP_OFF   0                       // hpart (fallback only)
#define HRED_OFF (NKSPL * NJ * NB)      // hred (fallback only)
#define W1T_OFF  2000000                 // W1T: read only by k1 (safe)
#define MAT_OFF  32000000                // Mat output (real output location)

// r13 LESSON (do not retry): depth-2 register pipeline spilled to scratch ->
// FETCH 74->314 MB, k1 43->272 us.
// r15 EXPERIMENT: W-stream moved from SMEM (s_load, 112-SGPR window cap ->
// lgkm serialization) to vector path (global_load_dwordx4 broadcast) via an
// opaque VGPR zero added to the W pointers. launch_bounds (256,3) for VGPR
// headroom (3 vs 4 blocks/CU measured neutral in r8/r9).

// ---------------------------------------------------------------------------
// k0: transpose W1[k][j] -> W1T[j][k] so k-quads are contiguous.
// ---------------------------------------------------------------------------
__global__ __launch_bounds__(256) void k0_transpose(const float* __restrict__ W1,
                                                    float* __restrict__ W1T) {
    const int k = blockIdx.x * 256 + threadIdx.x;
    if (k >= K_TOT) return;
    const float* src = W1 + (size_t)k * NJ;
#pragma unroll
    for (int j = 0; j < NJ; ++j)
        W1T[(size_t)j * K_TOT + k] = src[j];
}

// ---------------------------------------------------------------------------
// k1: split-K partials of h = img @ W1.  (r9 structure; W loads forced onto
// the VECTOR memory path -- per-lane identical addresses broadcast from L1,
// deep vmcnt window instead of the 112-SGPR-capped lgkm window.)
// ---------------------------------------------------------------------------
__global__ __launch_bounds__(256, 3) void k1_partial(const float* __restrict__ img,
                                                     const float* __restrict__ W1T,
                                                     float* __restrict__ hpart) {
    __shared__ float simg[2][64 * LDSTR];   // 2 x 17.0 KB
    const int tid  = threadIdx.x;
    const int bx   = blockIdx.x;          // k-chunk id [0,128)
    const int b0   = blockIdx.y << 6;     // batch base
    const int lane = tid & 63;
    const int j0   = __builtin_amdgcn_readfirstlane((tid >> 6) * 5);
    const int srow = tid >> 4;            // 0..15 (staging row)
    const int squad = tid & 15;           // 0..15 (staging quad col)

    const int q0  = (int)(((long long)bx * KQ_TOT) >> 7);        // quad start
    const int q1  = (int)(((long long)(bx + 1) * KQ_TOT) >> 7);  // quad end
    const int nqb = q1 - q0;                                     // 122 or 123
    const int nsteps = (nqb + 15) >> 4;                          // 8

    const float4* img4 = reinterpret_cast<const float4*>(img);
    const float4* W1T4 = reinterpret_cast<const float4*>(W1T);

    // Opaque VGPR zero: compiler cannot prove uniformity -> W pointers become
    // per-lane (identical) addresses -> global_load_dwordx4 broadcast path.
    int vz;
    asm volatile("v_mov_b32 %0, 0" : "=v"(vz));
    const float4* wj0 = W1T4 + (size_t)(j0 + 0) * KQ_TOT + vz;
    const float4* wj1 = W1T4 + (size_t)(j0 + 1) * KQ_TOT + vz;
    const float4* wj2 = W1T4 + (size_t)(j0 + 2) * KQ_TOT + vz;
    const float4* wj3 = W1T4 + (size_t)(j0 + 3) * KQ_TOT + vz;
    const float4* wj4 = W1T4 + (size_t)(j0 + 4) * KQ_TOT + vz;

    float acc0 = 0.f, acc1 = 0.f, acc2 = 0.f, acc3 = 0.f, acc4 = 0.f;

    // prologue: stage step 0 into buf 0 (16 quads, full for all chunks)
    {
        const int qg = q0 + squad;
#pragma unroll
        for (int rr = 0; rr < 4; ++rr) {
            const int row = srow + (rr << 4);
            *reinterpret_cast<float4*>(&simg[0][row * LDSTR + (squad << 2)]) =
                img4[(size_t)(b0 + row) * KQ_TOT + qg];
        }
    }
    __syncthreads();

    int cur = 0;
    for (int s = 0; s < nsteps; ++s) {
        // issue next step's global loads EARLY
        float4 r0, r1, r2, r3;
        bool dl = false;
        if (s + 1 < nsteps) {
            const int rem = nqb - (s + 1) * 16;
            const int cq  = (rem < 16) ? rem : 16;
            if (squad < cq) {
                dl = true;
                const size_t qg = (size_t)q0 + (s + 1) * 16 + squad;
                r0 = img4[(size_t)(b0 + srow +  0) * KQ_TOT + qg];
                r1 = img4[(size_t)(b0 + srow + 16) * KQ_TOT + qg];
                r2 = img4[(size_t)(b0 + srow + 32) * KQ_TOT + qg];
                r3 = img4[(size_t)(b0 + srow + 48) * KQ_TOT + qg];
            }
        }

        // compute current step: img from LDS lane-row, W via vector broadcast
        {
            const int rem = nqb - s * 16;
            const float* simgl = &simg[cur][lane * LDSTR];
            const int qb = q0 + s * 16;
            if (rem >= 16) {
#pragma unroll
                for (int q = 0; q < 16; ++q) {
                    const float4 iv = *reinterpret_cast<const float4*>(&simgl[q << 2]);
                    const int qi = qb + q;
                    const float4 w0 = wj0[qi];
                    const float4 w1 = wj1[qi];
                    const float4 w2 = wj2[qi];
                    const float4 w3 = wj3[qi];
                    const float4 w4 = wj4[qi];
                    acc0 += iv.x * w0.x + iv.y * w0.y + iv.z * w0.z + iv.w * w0.w;
                    acc1 += iv.x * w1.x + iv.y * w1.y + iv.z * w1.z + iv.w * w1.w;
                    acc2 += iv.x * w2.x + iv.y * w2.y + iv.z * w2.z + iv.w * w2.w;
                    acc3 += iv.x * w3.x + iv.y * w3.y + iv.z * w3.z + iv.w * w3.w;
                    acc4 += iv.x * w4.x + iv.y * w4.y + iv.z * w4.z + iv.w * w4.w;
                }
            } else {
                for (int q = 0; q < rem; ++q) {
                    const float4 iv = *reinterpret_cast<const float4*>(&simgl[q << 2]);
                    const int qi = qb + q;
                    const float4 w0 = wj0[qi];
                    const float4 w1 = wj1[qi];
                    const float4 w2 = wj2[qi];
                    const float4 w3 = wj3[qi];
                    const float4 w4 = wj4[qi];
                    acc0 += iv.x * w0.x + iv.y * w0.y + iv.z * w0.z + iv.w * w0.w;
                    acc1 += iv.x * w1.x + iv.y * w1.y + iv.z * w1.z + iv.w * w1.w;
                    acc2 += iv.x * w2.x + iv.y * w2.y + iv.z * w2.z + iv.w * w2.w;
                    acc3 += iv.x * w3.x + iv.y * w3.y + iv.z * w3.z + iv.w * w3.w;
                    acc4 += iv.x * w4.x + iv.y * w4.y + iv.z * w4.z + iv.w * w4.w;
                }
            }
        }

        // write next tile to the other buffer, then barrier
        if (dl) {
            float* d = &simg[cur ^ 1][srow * LDSTR + (squad << 2)];
            *reinterpret_cast<float4*>(&d[ 0 * LDSTR]) = r0;
            *reinterpret_cast<float4*>(&d[16 * LDSTR]) = r1;
            *reinterpret_cast<float4*>(&d[32 * LDSTR]) = r2;
            *reinterpret_cast<float4*>(&d[48 * LDSTR]) = r3;
        }
        __syncthreads();
        cur ^= 1;
    }

    // hpart[(bx*NJ + j)*NB + b] (coalesced across lanes)
    const int b = b0 + lane;
    float* dst = &hpart[(size_t)(bx * NJ + j0) * NB + b];
    dst[0 * NB] = acc0;
    dst[1 * NB] = acc1;
    dst[2 * NB] = acc2;
    dst[3 * NB] = acc3;
    dst[4 * NB] = acc4;
}

// ---------------------------------------------------------------------------
// k2a/k2b: fallback-only (used when ws_size is too small for hpart).
// ---------------------------------------------------------------------------
__global__ __launch_bounds__(256) void k2_reduce(const float* __restrict__ hpart,
                                                 float* __restrict__ hred) {
    const int b = blockIdx.x * 256 + threadIdx.x;
    const int j = blockIdx.y;
    float a = 0.f;
#pragma unroll 8
    for (int c = 0; c < NKSPL; ++c)
        a += hpart[(size_t)(c * NJ + j) * NB + b];
    hred[j * NB + b] = a;
}

__global__ __launch_bounds__(256) void k2_head(const float* __restrict__ hred,
                                               const float* __restrict__ b1,
                                               const float* __restrict__ W2,
                                               const float* __restrict__ b2,
                                               float* __restrict__ mat) {
    const int b = blockIdx.x * 256 + threadIdx.x;
    float z = b2[0];
#pragma unroll
    for (int j = 0; j < NJ; ++j) {
        const float h = tanhf(hred[j * NB + b] + b1[j]);
        z += h * W2[j];
    }
    const float sg = 1.0f / (1.0f + expf(-z));
    const float theta = sg * 6.28318530717958647692f;
    float sn, cn;
    sincosf(theta, &sn, &cn);
    float* m = mat + (size_t)b * 6;
    m[0] = cn; m[1] = -sn; m[2] = 0.f;
    m[3] = sn; m[4] = cn;  m[5] = 0.f;
}

// ---------------------------------------------------------------------------
// k3: fused reduce+head+affine_grid+grid_sample (r12 body, unchanged).
// ---------------------------------------------------------------------------
__device__ __forceinline__ unsigned int pack2bf(float a, float b) {
    __hip_bfloat16 ha = __float2bfloat16(a);
    __hip_bfloat16 hb = __float2bfloat16(b);
    const unsigned int ua = (unsigned int)__builtin_bit_cast(unsigned short, ha);
    const unsigned int ub = (unsigned int)__builtin_bit_cast(unsigned short, hb);
    return ua | (ub << 16);
}
#define BF_LO(u) __uint_as_float((u) << 16)
#define BF_HI(u) __uint_as_float((u) & 0xffff0000u)

template <bool FUSED>
__global__ __launch_bounds__(1024) void k3_sample_t(const float* __restrict__ img,
                                                    const float* __restrict__ hpart_or_mat,
                                                    const float* __restrict__ b1,
                                                    const float* __restrict__ W2,
                                                    const float* __restrict__ b2,
                                                    float* __restrict__ out) {
    __shared__ uint2 sch[HW_];          // [pixel] -> 4 channels packed bf16
    __shared__ float sred[NJ + 2];
    const int b   = blockIdx.x;
    const int tid = threadIdx.x;

    float cb, sb;
    if (FUSED) {
        if (tid < 640) {
            const int j = tid >> 5;        // 0..19
            const int l = tid & 31;        // 0..31
            float part = 0.f;
#pragma unroll
            for (int i = 0; i < 4; ++i) {
                const int c = (l << 2) + i; // 0..127
                part += hpart_or_mat[(size_t)(c * NJ + j) * NB + b];
            }
#pragma unroll
            for (int m = 16; m; m >>= 1)
                part += __shfl_xor(part, m);
            if (l == 0) sred[j] = part;
        }
        __syncthreads();
        if (tid == 0) {
            float z = b2[0];
#pragma unroll
            for (int j = 0; j < NJ; ++j)
                z += tanhf(sred[j] + b1[j]) * W2[j];
            const float sg = 1.0f / (1.0f + expf(-z));
            float sn, cn;
            sincosf(sg * 6.28318530717958647692f, &sn, &cn);
            float* m = out + MAT_OFF + (size_t)b * 6;   // Mat output
            m[0] = cn; m[1] = -sn; m[2] = 0.f;
            m[3] = sn; m[4] = cn;  m[5] = 0.f;
            sred[NJ]     = cn;
            sred[NJ + 1] = sn;
        }
        __syncthreads();
        cb = sred[NJ];
        sb = sred[NJ + 1];
    } else {
        cb = hpart_or_mat[(size_t)b * 6 + 4];
        sb = hpart_or_mat[(size_t)b * 6 + 3];
    }

    const size_t ib = (size_t)b * 4 * HW_;
    const float* p0 = img + ib;
    const float* p1 = p0 + HW_;
    const float* p2 = p1 + HW_;
    const float* p3 = p2 + HW_;

    // stage (vectorized): float4 per plane -> 4 packed uint2 LDS writes
    {
        const float4* v0 = reinterpret_cast<const float4*>(p0);
        const float4* v1 = reinterpret_cast<const float4*>(p1);
        const float4* v2 = reinterpret_cast<const float4*>(p2);
        const float4* v3 = reinterpret_cast<const float4*>(p3);
        const int nv = HW_ >> 2;          // 3906 float4s (= 15624 pixels)
        for (int i = tid; i < nv; i += 1024) {
            const float4 a = v0[i];
            const float4 bq = v1[i];
            const float4 c = v2[i];
            const float4 d = v3[i];
            const int base = i << 2;
            sch[base + 0] = make_uint2(pack2bf(a.x, bq.x), pack2bf(c.x, d.x));
            sch[base + 1] = make_uint2(pack2bf(a.y, bq.y), pack2bf(c.y, d.y));
            sch[base + 2] = make_uint2(pack2bf(a.z, bq.z), pack2bf(c.z, d.z));
            sch[base + 3] = make_uint2(pack2bf(a.w, bq.w), pack2bf(c.w, d.w));
        }
        if (tid == 0) {   // tail pixel 15624
            sch[HW_ - 1] = make_uint2(pack2bf(p0[HW_ - 1], p1[HW_ - 1]),
                                      pack2bf(p2[HW_ - 1], p3[HW_ - 1]));
        }
    }
    __syncthreads();

    float* o0 = out + ib;
    for (int p = tid; p < HW_; p += 1024) {
        const int y = p / WW_;
        const int x = p - y * WW_;

        const float gx = (float)x * (1.0f / 62.0f) - 1.0f;
        const float gy = (float)y * (1.0f / 62.0f) - 1.0f;
        const float fx = (cb * gx - sb * gy + 1.0f) * 62.0f;
        const float fy = (sb * gx + cb * gy + 1.0f) * 62.0f;

        const float x0f = floorf(fx), y0f = floorf(fy);
        const int x0 = (int)x0f, y0 = (int)y0f;
        const int x1 = x0 + 1, y1 = y0 + 1;
        const float wx1 = fx - x0f, wx0 = 1.0f - wx1;
        const float wy1 = fy - y0f, wy0 = 1.0f - wy1;

        const bool vx0 = ((unsigned)x0 <= 124u);
        const bool vx1 = ((unsigned)x1 <= 124u);
        const bool vy0 = ((unsigned)y0 <= 124u);
        const bool vy1 = ((unsigned)y1 <= 124u);

        const int cx0 = min(max(x0, 0), 124), cx1 = min(max(x1, 0), 124);
        const int cy0 = min(max(y0, 0), 124), cy1 = min(max(y1, 0), 124);

        const float m00 = (vx0 && vy0) ? wx0 * wy0 : 0.f;
        const float m01 = (vx1 && vy0) ? wx1 * wy0 : 0.f;
        const float m10 = (vx0 && vy1) ? wx0 * wy1 : 0.f;
        const float m11 = (vx1 && vy1) ? wx1 * wy1 : 0.f;

        const uint2 q00 = sch[cy0 * WW_ + cx0];
        const uint2 q01 = sch[cy0 * WW_ + cx1];
        const uint2 q10 = sch[cy1 * WW_ + cx0];
        const uint2 q11 = sch[cy1 * WW_ + cx1];

        float a0, a1, a2, a3;
        a0  = BF_LO(q00.x) * m00;  a1  = BF_HI(q00.x) * m00;
        a2  = BF_LO(q00.y) * m00;  a3  = BF_HI(q00.y) * m00;
        a0 += BF_LO(q01.x) * m01;  a1 += BF_HI(q01.x) * m01;
        a2 += BF_LO(q01.y) * m01;  a3 += BF_HI(q01.y) * m01;
        a0 += BF_LO(q10.x) * m10;  a1 += BF_HI(q10.x) * m10;
        a2 += BF_LO(q10.y) * m10;  a3 += BF_HI(q10.y) * m10;
        a0 += BF_LO(q11.x) * m11;  a1 += BF_HI(q11.x) * m11;
        a2 += BF_LO(q11.y) * m11;  a3 += BF_HI(q11.y) * m11;

        o0[p]            = a0;
        o0[p + 1 * HW_]  = a1;
        o0[p + 2 * HW_]  = a2;
        o0[p + 3 * HW_]  = a3;
    }
}

// ---------------------------------------------------------------------------
extern "C" void kernel_launch(void* const* d_in, const int* in_sizes, int n_in,
                              void* d_out, int out_size, void* d_ws, size_t ws_size,
                              hipStream_t stream) {
    const float* img = (const float*)d_in[0];
    const float* W1  = (const float*)d_in[1];
    const float* b1  = (const float*)d_in[2];
    const float* W2  = (const float*)d_in[3];
    const float* b2  = (const float*)d_in[4];
    float* out = (float*)d_out;

    float* W1T = out + W1T_OFF;   // read only by k1; overwritten later by k3
    const size_t hp_bytes = (size_t)NKSPL * NJ * NB * sizeof(float);  // 5.24 MB

    hipLaunchKernelGGL(k0_transpose, dim3((K_TOT + 255) / 256), dim3(256), 0, stream, W1, W1T);

    if (ws_size >= hp_bytes) {
        float* hpart = (float*)d_ws;
        hipLaunchKernelGGL(k1_partial, dim3(NKSPL, 8), dim3(256), 0, stream, img, W1T, hpart);
        hipLaunchKernelGGL(k3_sample_t<true>, dim3(NB), dim3(1024), 0, stream,
                           img, hpart, b1, W2, b2, out);
    } else {
        float* hpart = out + HP_OFF;
        float* hred  = out + HRED_OFF;
        float* mat   = out + MAT_OFF;
        hipLaunchKernelGGL(k1_partial, dim3(NKSPL, 8), dim3(256), 0, stream, img, W1T, hpart);
        hipLaunchKernelGGL(k2_reduce, dim3(2, NJ), dim3(256), 0, stream, hpart, hred);
        hipLaunchKernelGGL(k2_head, dim3(2), dim3(256), 0, stream, hred, b1, W2, b2, mat);
        hipLaunchKernelGGL(k3_sample_t<false>, dim3(NB), dim3(1024), 0, stream,
                           img, mat, b1, W2, b2, out);
    }
}

// Round 16
// 103.841 us; speedup vs baseline: 1.3769x; 1.3769x over previous
//
#include <hip/hip_runtime.h>
#include <hip/hip_bf16.h>
#include <math.h>

// Problem constants
#define K_TOT 62500      // C*H*W = 4*125*125
#define KQ_TOT 15625     // K_TOT / 4 (float4 quads per batch row)
#define NJ    20         // hidden width
#define NB    512        // batch
#define HW_   15625      // 125*125
#define WW_   125
#define NKSPL 128        // number of k1 blocks along K (contiguous chunks)
#define LDSTR 68         // padded LDS row stride (floats; 17 bank-quads -> conflict-free b128)

// scratch layout inside d_out's image region (only regions NOT read by k3):
#define HP_OFF   0                       // hpart (fallback only)
#define HRED_OFF (NKSPL * NJ * NB)      // hred (fallback only)
#define W1T_OFF  2000000                 // W1T: read only by k1 (safe)
#define MAT_OFF  32000000                // Mat output (real output location)

// k1 PERTURBATION LEDGER (body below = 43 us local optimum, 8 attempts):
//  r4 LDS-W (-5us) | r7 pack-W (-29) | r9 bounds4 (0) | r10 2-batch (-35)
//  r12 sched-cluster (0) | r13 reg-dbuf (-229, scratch spill)
//  r15 vector-W broadcast (-64, vmcnt stream mixing). DO NOT RETRY THESE.

// ---------------------------------------------------------------------------
// k0: transpose W1[k][j] -> W1T[j][k] so k-quads are contiguous.
// ---------------------------------------------------------------------------
__global__ __launch_bounds__(256) void k0_transpose(const float* __restrict__ W1,
                                                    float* __restrict__ W1T) {
    const int k = blockIdx.x * 256 + threadIdx.x;
    if (k >= K_TOT) return;
    const float* src = W1 + (size_t)k * NJ;
#pragma unroll
    for (int j = 0; j < NJ; ++j)
        W1T[(size_t)j * K_TOT + k] = src[j];
}

// ---------------------------------------------------------------------------
// k1: split-K partials of h = img @ W1.  (r12 measured-best body, ~43 us)
// grid = (128 contiguous k-chunks, 8 batch-groups), block = 256 (4 waves).
// img tile [64 rows][16 quads] double-buffered in LDS (issue-early /
// write-late, 1-deep). W1T read as wave-uniform float4 (SMEM stream) --
// scalar path keeps W off the img vmcnt counter.
// ---------------------------------------------------------------------------
__global__ __launch_bounds__(256, 4) void k1_partial(const float* __restrict__ img,
                                                     const float* __restrict__ W1T,
                                                     float* __restrict__ hpart) {
    __shared__ float simg[2][64 * LDSTR];   // 2 x 17.0 KB
    const int tid  = threadIdx.x;
    const int bx   = blockIdx.x;          // k-chunk id [0,128)
    const int b0   = blockIdx.y << 6;     // batch base
    const int lane = tid & 63;
    const int j0   = __builtin_amdgcn_readfirstlane((tid >> 6) * 5);
    const int srow = tid >> 4;            // 0..15 (staging row)
    const int squad = tid & 15;           // 0..15 (staging quad col)

    const int q0  = (int)(((long long)bx * KQ_TOT) >> 7);        // quad start
    const int q1  = (int)(((long long)(bx + 1) * KQ_TOT) >> 7);  // quad end
    const int nqb = q1 - q0;                                     // 122 or 123
    const int nsteps = (nqb + 15) >> 4;                          // 8

    const float4* img4 = reinterpret_cast<const float4*>(img);
    const float4* W1T4 = reinterpret_cast<const float4*>(W1T);
    const float4* wj0 = W1T4 + (size_t)(j0 + 0) * KQ_TOT;
    const float4* wj1 = W1T4 + (size_t)(j0 + 1) * KQ_TOT;
    const float4* wj2 = W1T4 + (size_t)(j0 + 2) * KQ_TOT;
    const float4* wj3 = W1T4 + (size_t)(j0 + 3) * KQ_TOT;
    const float4* wj4 = W1T4 + (size_t)(j0 + 4) * KQ_TOT;

    float acc0 = 0.f, acc1 = 0.f, acc2 = 0.f, acc3 = 0.f, acc4 = 0.f;

    // prologue: stage step 0 into buf 0 (16 quads, full for all chunks)
    {
        const int qg = q0 + squad;
#pragma unroll
        for (int rr = 0; rr < 4; ++rr) {
            const int row = srow + (rr << 4);
            *reinterpret_cast<float4*>(&simg[0][row * LDSTR + (squad << 2)]) =
                img4[(size_t)(b0 + row) * KQ_TOT + qg];
        }
    }
    __syncthreads();

    int cur = 0;
    for (int s = 0; s < nsteps; ++s) {
        // issue next step's global loads EARLY (vmcnt stream: img only)
        float4 r0, r1, r2, r3;
        bool dl = false;
        if (s + 1 < nsteps) {
            const int rem = nqb - (s + 1) * 16;
            const int cq  = (rem < 16) ? rem : 16;
            if (squad < cq) {
                dl = true;
                const size_t qg = (size_t)q0 + (s + 1) * 16 + squad;
                r0 = img4[(size_t)(b0 + srow +  0) * KQ_TOT + qg];
                r1 = img4[(size_t)(b0 + srow + 16) * KQ_TOT + qg];
                r2 = img4[(size_t)(b0 + srow + 32) * KQ_TOT + qg];
                r3 = img4[(size_t)(b0 + srow + 48) * KQ_TOT + qg];
            }
        }

        // compute current step: img from LDS lane-row, W uniform (SMEM stream)
        {
            const int rem = nqb - s * 16;
            const float* simgl = &simg[cur][lane * LDSTR];
            const int qb = q0 + s * 16;
            if (rem >= 16) {
#pragma unroll
                for (int h = 0; h < 2; ++h) {
                    float4 iv[8];
#pragma unroll
                    for (int q = 0; q < 8; ++q)
                        iv[q] = *reinterpret_cast<const float4*>(&simgl[(h * 8 + q) << 2]);
                    __builtin_amdgcn_sched_barrier(0);
#pragma unroll
                    for (int q = 0; q < 8; ++q) {
                        const int qi = qb + h * 8 + q;
                        const float4 w0 = wj0[qi];
                        const float4 w1 = wj1[qi];
                        const float4 w2 = wj2[qi];
                        const float4 w3 = wj3[qi];
                        const float4 w4 = wj4[qi];
                        acc0 += iv[q].x * w0.x + iv[q].y * w0.y + iv[q].z * w0.z + iv[q].w * w0.w;
                        acc1 += iv[q].x * w1.x + iv[q].y * w1.y + iv[q].z * w1.z + iv[q].w * w1.w;
                        acc2 += iv[q].x * w2.x + iv[q].y * w2.y + iv[q].z * w2.z + iv[q].w * w2.w;
                        acc3 += iv[q].x * w3.x + iv[q].y * w3.y + iv[q].z * w3.z + iv[q].w * w3.w;
                        acc4 += iv[q].x * w4.x + iv[q].y * w4.y + iv[q].z * w4.z + iv[q].w * w4.w;
                    }
                }
            } else {
                for (int q = 0; q < rem; ++q) {
                    const float4 iv = *reinterpret_cast<const float4*>(&simgl[q << 2]);
                    const int qi = qb + q;
                    const float4 w0 = wj0[qi];
                    const float4 w1 = wj1[qi];
                    const float4 w2 = wj2[qi];
                    const float4 w3 = wj3[qi];
                    const float4 w4 = wj4[qi];
                    acc0 += iv.x * w0.x + iv.y * w0.y + iv.z * w0.z + iv.w * w0.w;
                    acc1 += iv.x * w1.x + iv.y * w1.y + iv.z * w1.z + iv.w * w1.w;
                    acc2 += iv.x * w2.x + iv.y * w2.y + iv.z * w2.z + iv.w * w2.w;
                    acc3 += iv.x * w3.x + iv.y * w3.y + iv.z * w3.z + iv.w * w3.w;
                    acc4 += iv.x * w4.x + iv.y * w4.y + iv.z * w4.z + iv.w * w4.w;
                }
            }
        }

        // write next tile to the other buffer, then barrier
        if (dl) {
            float* d = &simg[cur ^ 1][srow * LDSTR + (squad << 2)];
            *reinterpret_cast<float4*>(&d[ 0 * LDSTR]) = r0;
            *reinterpret_cast<float4*>(&d[16 * LDSTR]) = r1;
            *reinterpret_cast<float4*>(&d[32 * LDSTR]) = r2;
            *reinterpret_cast<float4*>(&d[48 * LDSTR]) = r3;
        }
        __syncthreads();
        cur ^= 1;
    }

    // hpart[(bx*NJ + j)*NB + b] (coalesced across lanes)
    const int b = b0 + lane;
    float* dst = &hpart[(size_t)(bx * NJ + j0) * NB + b];
    dst[0 * NB] = acc0;
    dst[1 * NB] = acc1;
    dst[2 * NB] = acc2;
    dst[3 * NB] = acc3;
    dst[4 * NB] = acc4;
}

// ---------------------------------------------------------------------------
// k2a/k2b: fallback-only (used when ws_size is too small for hpart).
// ---------------------------------------------------------------------------
__global__ __launch_bounds__(256) void k2_reduce(const float* __restrict__ hpart,
                                                 float* __restrict__ hred) {
    const int b = blockIdx.x * 256 + threadIdx.x;
    const int j = blockIdx.y;
    float a = 0.f;
#pragma unroll 8
    for (int c = 0; c < NKSPL; ++c)
        a += hpart[(size_t)(c * NJ + j) * NB + b];
    hred[j * NB + b] = a;
}

__global__ __launch_bounds__(256) void k2_head(const float* __restrict__ hred,
                                               const float* __restrict__ b1,
                                               const float* __restrict__ W2,
                                               const float* __restrict__ b2,
                                               float* __restrict__ mat) {
    const int b = blockIdx.x * 256 + threadIdx.x;
    float z = b2[0];
#pragma unroll
    for (int j = 0; j < NJ; ++j) {
        const float h = tanhf(hred[j * NB + b] + b1[j]);
        z += h * W2[j];
    }
    const float sg = 1.0f / (1.0f + expf(-z));
    const float theta = sg * 6.28318530717958647692f;
    float sn, cn;
    sincosf(theta, &sn, &cn);
    float* m = mat + (size_t)b * 6;
    m[0] = cn; m[1] = -sn; m[2] = 0.f;
    m[3] = sn; m[4] = cn;  m[5] = 0.f;
}

// ---------------------------------------------------------------------------
// k3: fused reduce+head+affine_grid+grid_sample (r12 body, unchanged).
// ---------------------------------------------------------------------------
__device__ __forceinline__ unsigned int pack2bf(float a, float b) {
    __hip_bfloat16 ha = __float2bfloat16(a);
    __hip_bfloat16 hb = __float2bfloat16(b);
    const unsigned int ua = (unsigned int)__builtin_bit_cast(unsigned short, ha);
    const unsigned int ub = (unsigned int)__builtin_bit_cast(unsigned short, hb);
    return ua | (ub << 16);
}
#define BF_LO(u) __uint_as_float((u) << 16)
#define BF_HI(u) __uint_as_float((u) & 0xffff0000u)

template <bool FUSED>
__global__ __launch_bounds__(1024) void k3_sample_t(const float* __restrict__ img,
                                                    const float* __restrict__ hpart_or_mat,
                                                    const float* __restrict__ b1,
                                                    const float* __restrict__ W2,
                                                    const float* __restrict__ b2,
                                                    float* __restrict__ out) {
    __shared__ uint2 sch[HW_];          // [pixel] -> 4 channels packed bf16
    __shared__ float sred[NJ + 2];
    const int b   = blockIdx.x;
    const int tid = threadIdx.x;

    float cb, sb;
    if (FUSED) {
        if (tid < 640) {
            const int j = tid >> 5;        // 0..19
            const int l = tid & 31;        // 0..31
            float part = 0.f;
#pragma unroll
            for (int i = 0; i < 4; ++i) {
                const int c = (l << 2) + i; // 0..127
                part += hpart_or_mat[(size_t)(c * NJ + j) * NB + b];
            }
#pragma unroll
            for (int m = 16; m; m >>= 1)
                part += __shfl_xor(part, m);
            if (l == 0) sred[j] = part;
        }
        __syncthreads();
        if (tid == 0) {
            float z = b2[0];
#pragma unroll
            for (int j = 0; j < NJ; ++j)
                z += tanhf(sred[j] + b1[j]) * W2[j];
            const float sg = 1.0f / (1.0f + expf(-z));
            float sn, cn;
            sincosf(sg * 6.28318530717958647692f, &sn, &cn);
            float* m = out + MAT_OFF + (size_t)b * 6;   // Mat output
            m[0] = cn; m[1] = -sn; m[2] = 0.f;
            m[3] = sn; m[4] = cn;  m[5] = 0.f;
            sred[NJ]     = cn;
            sred[NJ + 1] = sn;
        }
        __syncthreads();
        cb = sred[NJ];
        sb = sred[NJ + 1];
    } else {
        cb = hpart_or_mat[(size_t)b * 6 + 4];
        sb = hpart_or_mat[(size_t)b * 6 + 3];
    }

    const size_t ib = (size_t)b * 4 * HW_;
    const float* p0 = img + ib;
    const float* p1 = p0 + HW_;
    const float* p2 = p1 + HW_;
    const float* p3 = p2 + HW_;

    // stage (vectorized): float4 per plane -> 4 packed uint2 LDS writes
    {
        const float4* v0 = reinterpret_cast<const float4*>(p0);
        const float4* v1 = reinterpret_cast<const float4*>(p1);
        const float4* v2 = reinterpret_cast<const float4*>(p2);
        const float4* v3 = reinterpret_cast<const float4*>(p3);
        const int nv = HW_ >> 2;          // 3906 float4s (= 15624 pixels)
        for (int i = tid; i < nv; i += 1024) {
            const float4 a = v0[i];
            const float4 bq = v1[i];
            const float4 c = v2[i];
            const float4 d = v3[i];
            const int base = i << 2;
            sch[base + 0] = make_uint2(pack2bf(a.x, bq.x), pack2bf(c.x, d.x));
            sch[base + 1] = make_uint2(pack2bf(a.y, bq.y), pack2bf(c.y, d.y));
            sch[base + 2] = make_uint2(pack2bf(a.z, bq.z), pack2bf(c.z, d.z));
            sch[base + 3] = make_uint2(pack2bf(a.w, bq.w), pack2bf(c.w, d.w));
        }
        if (tid == 0) {   // tail pixel 15624
            sch[HW_ - 1] = make_uint2(pack2bf(p0[HW_ - 1], p1[HW_ - 1]),
                                      pack2bf(p2[HW_ - 1], p3[HW_ - 1]));
        }
    }
    __syncthreads();

    float* o0 = out + ib;
    for (int p = tid; p < HW_; p += 1024) {
        const int y = p / WW_;
        const int x = p - y * WW_;

        const float gx = (float)x * (1.0f / 62.0f) - 1.0f;
        const float gy = (float)y * (1.0f / 62.0f) - 1.0f;
        const float fx = (cb * gx - sb * gy + 1.0f) * 62.0f;
        const float fy = (sb * gx + cb * gy + 1.0f) * 62.0f;

        const float x0f = floorf(fx), y0f = floorf(fy);
        const int x0 = (int)x0f, y0 = (int)y0f;
        const int x1 = x0 + 1, y1 = y0 + 1;
        const float wx1 = fx - x0f, wx0 = 1.0f - wx1;
        const float wy1 = fy - y0f, wy0 = 1.0f - wy1;

        const bool vx0 = ((unsigned)x0 <= 124u);
        const bool vx1 = ((unsigned)x1 <= 124u);
        const bool vy0 = ((unsigned)y0 <= 124u);
        const bool vy1 = ((unsigned)y1 <= 124u);

        const int cx0 = min(max(x0, 0), 124), cx1 = min(max(x1, 0), 124);
        const int cy0 = min(max(y0, 0), 124), cy1 = min(max(y1, 0), 124);

        const float m00 = (vx0 && vy0) ? wx0 * wy0 : 0.f;
        const float m01 = (vx1 && vy0) ? wx1 * wy0 : 0.f;
        const float m10 = (vx0 && vy1) ? wx0 * wy1 : 0.f;
        const float m11 = (vx1 && vy1) ? wx1 * wy1 : 0.f;

        const uint2 q00 = sch[cy0 * WW_ + cx0];
        const uint2 q01 = sch[cy0 * WW_ + cx1];
        const uint2 q10 = sch[cy1 * WW_ + cx0];
        const uint2 q11 = sch[cy1 * WW_ + cx1];

        float a0, a1, a2, a3;
        a0  = BF_LO(q00.x) * m00;  a1  = BF_HI(q00.x) * m00;
        a2  = BF_LO(q00.y) * m00;  a3  = BF_HI(q00.y) * m00;
        a0 += BF_LO(q01.x) * m01;  a1 += BF_HI(q01.x) * m01;
        a2 += BF_LO(q01.y) * m01;  a3 += BF_HI(q01.y) * m01;
        a0 += BF_LO(q10.x) * m10;  a1 += BF_HI(q10.x) * m10;
        a2 += BF_LO(q10.y) * m10;  a3 += BF_HI(q10.y) * m10;
        a0 += BF_LO(q11.x) * m11;  a1 += BF_HI(q11.x) * m11;
        a2 += BF_LO(q11.y) * m11;  a3 += BF_HI(q11.y) * m11;

        o0[p]            = a0;
        o0[p + 1 * HW_]  = a1;
        o0[p + 2 * HW_]  = a2;
        o0[p + 3 * HW_]  = a3;
    }
}

// ---------------------------------------------------------------------------
extern "C" void kernel_launch(void* const* d_in, const int* in_sizes, int n_in,
                              void* d_out, int out_size, void* d_ws, size_t ws_size,
                              hipStream_t stream) {
    const float* img = (const float*)d_in[0];
    const float* W1  = (const float*)d_in[1];
    const float* b1  = (const float*)d_in[2];
    const float* W2  = (const float*)d_in[3];
    const float* b2  = (const float*)d_in[4];
    float* out = (float*)d_out;

    float* W1T = out + W1T_OFF;   // read only by k1; overwritten later by k3
    const size_t hp_bytes = (size_t)NKSPL * NJ * NB * sizeof(float);  // 5.24 MB

    hipLaunchKernelGGL(k0_transpose, dim3((K_TOT + 255) / 256), dim3(256), 0, stream, W1, W1T);

    if (ws_size >= hp_bytes) {
        float* hpart = (float*)d_ws;
        hipLaunchKernelGGL(k1_partial, dim3(NKSPL, 8), dim3(256), 0, stream, img, W1T, hpart);
        hipLaunchKernelGGL(k3_sample_t<true>, dim3(NB), dim3(1024), 0, stream,
                           img, hpart, b1, W2, b2, out);
    } else {
        float* hpart = out + HP_OFF;
        float* hred  = out + HRED_OFF;
        float* mat   = out + MAT_OFF;
        hipLaunchKernelGGL(k1_partial, dim3(NKSPL, 8), dim3(256), 0, stream, img, W1T, hpart);
        hipLaunchKernelGGL(k2_reduce, dim3(2, NJ), dim3(256), 0, stream, hpart, hred);
        hipLaunchKernelGGL(k2_head, dim3(2), dim3(256), 0, stream, hred, b1, W2, b2, mat);
        hipLaunchKernelGGL(k3_sample_t<false>, dim3(NB), dim3(1024), 0, stream,
                           img, mat, b1, W2, b2, out);
    }
}